// Round 2
// baseline (201.124 us; speedup 1.0000x reference)
//
#include <hip/hip_runtime.h>

#define NC 4
#define GATHER_BETA 3.0f
#define SCATTER_BETA 1e10f

__global__ __launch_bounds__(256) void predlayer_fused(
    const float* __restrict__ states_h,
    const float* __restrict__ states_c,
    const float* __restrict__ new_h,
    const float* __restrict__ new_c,
    const float* __restrict__ logits,
    float* __restrict__ out,
    long long total,      // bs*h*w*oc
    long long span)       // h*w*oc (elements per batch)
{
    long long idx4 = (((long long)blockIdx.x * blockDim.x) + threadIdx.x) * 4;
    if (idx4 >= total) return;

    const int b = (int)(idx4 / span);

    // --- tiny per-batch softmaxes (wave-uniform: whole block shares b) ---
    float l[NC];
#pragma unroll
    for (int c = 0; c < NC; ++c) l[c] = logits[b * NC + c];

    // gather weights: softmax(logits * 3) — safe arg range, verified passing
    float g[NC];
    float mg = -1e30f;
#pragma unroll
    for (int c = 0; c < NC; ++c) { g[c] = l[c] * GATHER_BETA; mg = fmaxf(mg, g[c]); }
    float sg = 0.0f;
#pragma unroll
    for (int c = 0; c < NC; ++c) { g[c] = expf(g[c] - mg); sg += g[c]; }
    float inv_sg = 1.0f / sg;
#pragma unroll
    for (int c = 0; c < NC; ++c) g[c] *= inv_sg;

    // scatter mask: softmax(logits * 1e10) == exact one-hot (ties split).
    // Computed WITHOUT exp of +/-1e10-scale args (NaN-safe, bit-equal to
    // the f32 reference softmax for non-degenerate logits).
    float s[NC];
    float mm = -1e30f;
#pragma unroll
    for (int c = 0; c < NC; ++c) { s[c] = l[c] * SCATTER_BETA; mm = fmaxf(mm, s[c]); }
    float m[NC];
    float cnt = 0.0f;
#pragma unroll
    for (int c = 0; c < NC; ++c) { m[c] = (s[c] == mm) ? 1.0f : 0.0f; cnt += m[c]; }
    float inv_cnt = 1.0f / cnt;
#pragma unroll
    for (int c = 0; c < NC; ++c) m[c] *= inv_cnt;

    // --- streaming body: float4 per thread ---
    const float4 nh = *reinterpret_cast<const float4*>(new_h + idx4);
    const float4 ncv = *reinterpret_cast<const float4*>(new_c + idx4);

    float* out_gh = out;
    float* out_gc = out + total;
    float* out_uh = out + 2 * total;
    float* out_uc = out + 6 * total;

    float4 gh = make_float4(0.f, 0.f, 0.f, 0.f);
    float4 gc = make_float4(0.f, 0.f, 0.f, 0.f);

#pragma unroll
    for (int c = 0; c < NC; ++c) {
        const long long off = (long long)c * total + idx4;
        const float4 sh = *reinterpret_cast<const float4*>(states_h + off);
        const float4 sc = *reinterpret_cast<const float4*>(states_c + off);

        gh.x += g[c] * sh.x; gh.y += g[c] * sh.y; gh.z += g[c] * sh.z; gh.w += g[c] * sh.w;
        gc.x += g[c] * sc.x; gc.y += g[c] * sc.y; gc.z += g[c] * sc.z; gc.w += g[c] * sc.w;

        const float w1 = 1.0f - m[c];
        float4 uh, uc;
        uh.x = sh.x * w1 + nh.x * m[c];
        uh.y = sh.y * w1 + nh.y * m[c];
        uh.z = sh.z * w1 + nh.z * m[c];
        uh.w = sh.w * w1 + nh.w * m[c];
        uc.x = sc.x * w1 + ncv.x * m[c];
        uc.y = sc.y * w1 + ncv.y * m[c];
        uc.z = sc.z * w1 + ncv.z * m[c];
        uc.w = sc.w * w1 + ncv.w * m[c];

        *reinterpret_cast<float4*>(out_uh + off) = uh;
        *reinterpret_cast<float4*>(out_uc + off) = uc;
    }

    *reinterpret_cast<float4*>(out_gh + idx4) = gh;
    *reinterpret_cast<float4*>(out_gc + idx4) = gc;
}

extern "C" void kernel_launch(void* const* d_in, const int* in_sizes, int n_in,
                              void* d_out, int out_size, void* d_ws, size_t ws_size,
                              hipStream_t stream) {
    const float* states_h = (const float*)d_in[0];
    const float* states_c = (const float*)d_in[1];
    const float* new_h    = (const float*)d_in[2];
    const float* new_c    = (const float*)d_in[3];
    const float* logits   = (const float*)d_in[4];
    float* out = (float*)d_out;

    const long long total = in_sizes[2];               // bs*h*w*oc
    const long long nc    = in_sizes[0] / total;       // 4
    const long long bs    = in_sizes[4] / nc;          // 16
    const long long span  = total / bs;                // h*w*oc

    (void)nc; // kernel hard-codes NC=4 (matches reference)

    const int block = 256;
    const long long n4 = total / 4;                    // total divisible by 4
    const int grid = (int)((n4 + block - 1) / block);

    predlayer_fused<<<grid, block, 0, stream>>>(
        states_h, states_c, new_h, new_c, logits, out, total, span);
}

// Round 3
// 190.921 us; speedup vs baseline: 1.0534x; 1.0534x over previous
//
#include <hip/hip_runtime.h>

#define NC 4
#define GATHER_BETA 3.0f
#define SCATTER_BETA 1e10f

typedef float f4 __attribute__((ext_vector_type(4)));

__device__ __forceinline__ f4 ntload(const float* p) {
    return __builtin_nontemporal_load(reinterpret_cast<const f4*>(p));
}
__device__ __forceinline__ void ntstore(float* p, f4 v) {
    __builtin_nontemporal_store(v, reinterpret_cast<f4*>(p));
}

// Per-batch weights: gather softmax (beta=3) and scatter one-hot (beta=1e10,
// computed exp-free: exact argmax one-hot with tie-splitting — bit-equal to
// the f32 reference softmax for these magnitudes).
__device__ __forceinline__ void make_weights(const float* __restrict__ logits,
                                             int b, float* g, float* m) {
    float l[NC];
#pragma unroll
    for (int c = 0; c < NC; ++c) l[c] = logits[b * NC + c];

    float mg = -1e30f;
#pragma unroll
    for (int c = 0; c < NC; ++c) { g[c] = l[c] * GATHER_BETA; mg = fmaxf(mg, g[c]); }
    float sg = 0.0f;
#pragma unroll
    for (int c = 0; c < NC; ++c) { g[c] = expf(g[c] - mg); sg += g[c]; }
    float inv_sg = 1.0f / sg;
#pragma unroll
    for (int c = 0; c < NC; ++c) g[c] *= inv_sg;

    float s[NC];
    float mm = -1e30f;
#pragma unroll
    for (int c = 0; c < NC; ++c) { s[c] = l[c] * SCATTER_BETA; mm = fmaxf(mm, s[c]); }
    float cnt = 0.0f;
#pragma unroll
    for (int c = 0; c < NC; ++c) { m[c] = (s[c] == mm) ? 1.0f : 0.0f; cnt += m[c]; }
    float inv_cnt = 1.0f / cnt;
#pragma unroll
    for (int c = 0; c < NC; ++c) m[c] *= inv_cnt;
}

__device__ __forceinline__ void process_chunk(
    const float* __restrict__ states_h, const float* __restrict__ states_c,
    const float* __restrict__ new_h,    const float* __restrict__ new_c,
    float* __restrict__ out, long long total, long long idx4,
    const float* g, const float* m)
{
    const f4 nh  = ntload(new_h + idx4);
    const f4 ncv = ntload(new_c + idx4);

    float* out_gh = out;
    float* out_gc = out + total;
    float* out_uh = out + 2 * total;
    float* out_uc = out + 6 * total;

    f4 gh = (f4){0.f, 0.f, 0.f, 0.f};
    f4 gc = (f4){0.f, 0.f, 0.f, 0.f};

#pragma unroll
    for (int c = 0; c < NC; ++c) {
        const long long off = (long long)c * total + idx4;
        const f4 sh = ntload(states_h + off);
        const f4 sc = ntload(states_c + off);

        gh += g[c] * sh;
        gc += g[c] * sc;

        const float w1 = 1.0f - m[c];
        ntstore(out_uh + off, sh * w1 + nh  * m[c]);
        ntstore(out_uc + off, sc * w1 + ncv * m[c]);
    }

    ntstore(out_gh + idx4, gh);
    ntstore(out_gc + idx4, gc);
}

__global__ __launch_bounds__(256) void predlayer_fused(
    const float* __restrict__ states_h,
    const float* __restrict__ states_c,
    const float* __restrict__ new_h,
    const float* __restrict__ new_c,
    const float* __restrict__ logits,
    float* __restrict__ out,
    long long total,      // bs*h*w*oc
    long long span,       // h*w*oc
    int db)               // batch delta for second chunk = bs/2
{
    const long long half = total >> 1;   // total/2, float4-aligned (bs even)
    long long idx4 = (((long long)blockIdx.x * blockDim.x) + threadIdx.x) * 4;
    if (idx4 >= half) return;

    const int b0 = (int)(idx4 / span);   // chunk B batch = b0 + db, no 2nd div
    const int b1 = b0 + db;

    float g0[NC], m0[NC], g1[NC], m1[NC];
    make_weights(logits, b0, g0, m0);
    make_weights(logits, b1, g1, m1);

    process_chunk(states_h, states_c, new_h, new_c, out, total, idx4,        g0, m0);
    process_chunk(states_h, states_c, new_h, new_c, out, total, idx4 + half, g1, m1);
}

extern "C" void kernel_launch(void* const* d_in, const int* in_sizes, int n_in,
                              void* d_out, int out_size, void* d_ws, size_t ws_size,
                              hipStream_t stream) {
    const float* states_h = (const float*)d_in[0];
    const float* states_c = (const float*)d_in[1];
    const float* new_h    = (const float*)d_in[2];
    const float* new_c    = (const float*)d_in[3];
    const float* logits   = (const float*)d_in[4];
    float* out = (float*)d_out;

    const long long total = in_sizes[2];               // bs*h*w*oc
    const long long nc    = in_sizes[0] / total;       // 4
    const long long bs    = in_sizes[4] / nc;          // 16
    const long long span  = total / bs;                // h*w*oc

    const int block = 256;
    const long long n4 = total / 8;                    // float4 chunks per half
    const int grid = (int)((n4 + block - 1) / block);

    predlayer_fused<<<grid, block, 0, stream>>>(
        states_h, states_c, new_h, new_c, logits, out, total, span, (int)(bs / 2));
}

// Round 4
// 190.510 us; speedup vs baseline: 1.0557x; 1.0022x over previous
//
#include <hip/hip_runtime.h>

#define NC 4
#define GATHER_BETA 3.0f
#define SCATTER_BETA 1e10f

typedef float f4 __attribute__((ext_vector_type(4)));

__device__ __forceinline__ f4 ntload(const float* p) {
    return __builtin_nontemporal_load(reinterpret_cast<const f4*>(p));
}
__device__ __forceinline__ void ntstore(float* p, f4 v) {
    __builtin_nontemporal_store(v, reinterpret_cast<f4*>(p));
}

// Per-batch weights: gather softmax (beta=3) and scatter one-hot (beta=1e10,
// computed exp-free: exact argmax one-hot with tie-splitting — bit-equal to
// the f32 reference softmax for these magnitudes).
__device__ __forceinline__ void make_weights(const float* __restrict__ logits,
                                             int b, float* g, float* m) {
    float l[NC];
#pragma unroll
    for (int c = 0; c < NC; ++c) l[c] = logits[b * NC + c];

    float mg = -1e30f;
#pragma unroll
    for (int c = 0; c < NC; ++c) { g[c] = l[c] * GATHER_BETA; mg = fmaxf(mg, g[c]); }
    float sg = 0.0f;
#pragma unroll
    for (int c = 0; c < NC; ++c) { g[c] = expf(g[c] - mg); sg += g[c]; }
    float inv_sg = 1.0f / sg;
#pragma unroll
    for (int c = 0; c < NC; ++c) g[c] *= inv_sg;

    float s[NC];
    float mm = -1e30f;
#pragma unroll
    for (int c = 0; c < NC; ++c) { s[c] = l[c] * SCATTER_BETA; mm = fmaxf(mm, s[c]); }
    float cnt = 0.0f;
#pragma unroll
    for (int c = 0; c < NC; ++c) { m[c] = (s[c] == mm) ? 1.0f : 0.0f; cnt += m[c]; }
    float inv_cnt = 1.0f / cnt;
#pragma unroll
    for (int c = 0; c < NC; ++c) m[c] *= inv_cnt;
}

__device__ __forceinline__ void process_chunk(
    const float* __restrict__ states_h, const float* __restrict__ states_c,
    const float* __restrict__ new_h,    const float* __restrict__ new_c,
    float* __restrict__ out, long long total, long long idx4,
    const float* g, const float* m)
{
    const f4 nh  = ntload(new_h + idx4);
    const f4 ncv = ntload(new_c + idx4);

    float* out_gh = out;
    float* out_gc = out + total;
    float* out_uh = out + 2 * total;
    float* out_uc = out + 6 * total;

    f4 gh = (f4){0.f, 0.f, 0.f, 0.f};
    f4 gc = (f4){0.f, 0.f, 0.f, 0.f};

#pragma unroll
    for (int c = 0; c < NC; ++c) {
        const long long off = (long long)c * total + idx4;
        const f4 sh = ntload(states_h + off);
        const f4 sc = ntload(states_c + off);

        gh += g[c] * sh;
        gc += g[c] * sc;

        const float w1 = 1.0f - m[c];
        ntstore(out_uh + off, sh * w1 + nh  * m[c]);
        ntstore(out_uc + off, sc * w1 + ncv * m[c]);
    }

    ntstore(out_gh + idx4, gh);
    ntstore(out_gc + idx4, gc);
}

__global__ __launch_bounds__(256) void predlayer_fused(
    const float* __restrict__ states_h,
    const float* __restrict__ states_c,
    const float* __restrict__ new_h,
    const float* __restrict__ new_c,
    const float* __restrict__ logits,
    float* __restrict__ out,
    long long total,      // bs*h*w*oc
    long long span,       // h*w*oc
    int db)               // batch delta per chunk = bs/4
{
    const long long quarter = total >> 2;  // bs divisible by 4
    long long idx4 = (((long long)blockIdx.x * blockDim.x) + threadIdx.x) * 4;
    if (idx4 >= quarter) return;

    const int b0 = (int)(idx4 / span);     // single i64 div; chunk k batch = b0 + k*db

#pragma unroll
    for (int k = 0; k < 4; ++k) {
        float g[NC], m[NC];
        make_weights(logits, b0 + k * db, g, m);
        process_chunk(states_h, states_c, new_h, new_c, out, total,
                      idx4 + (long long)k * quarter, g, m);
    }
}

extern "C" void kernel_launch(void* const* d_in, const int* in_sizes, int n_in,
                              void* d_out, int out_size, void* d_ws, size_t ws_size,
                              hipStream_t stream) {
    const float* states_h = (const float*)d_in[0];
    const float* states_c = (const float*)d_in[1];
    const float* new_h    = (const float*)d_in[2];
    const float* new_c    = (const float*)d_in[3];
    const float* logits   = (const float*)d_in[4];
    float* out = (float*)d_out;

    const long long total = in_sizes[2];               // bs*h*w*oc
    const long long nc    = in_sizes[0] / total;       // 4
    const long long bs    = in_sizes[4] / nc;          // 16
    const long long span  = total / bs;                // h*w*oc

    const int block = 256;
    const long long nthreads = total / 16;             // 4 float4 chunks per thread
    const int grid = (int)((nthreads + block - 1) / block);

    predlayer_fused<<<grid, block, 0, stream>>>(
        states_h, states_c, new_h, new_c, logits, out, total, span, (int)(bs / 4));
}